// Round 3
// baseline (19015.404 us; speedup 1.0000x reference)
//
#include <hip/hip_runtime.h>
#include <hip/hip_cooperative_groups.h>
#include <math.h>

namespace cg = cooperative_groups;

#define BB 64
#define SS 1024
#define CC 512
#define VV 140
#define AA 512
#define HH 512
#define TT 128
#define G4 2048   // 4*H
#define VA 652    // V+A
#define LP 144    // lpart stride (140 padded)

// ---------------------------------------------------------------------------
// One-time precompute kernels
// ---------------------------------------------------------------------------

__global__ void k_small(const float* __restrict__ Hc, const float* __restrict__ Hcb,
                        const float* __restrict__ Ic, const float* __restrict__ Icb,
                        float* __restrict__ p0, float* __restrict__ v0,
                        float* __restrict__ s0) {
    int t = threadIdx.x;  // 512
    float av = 0.f, pv = 0.f;
    for (int a = 0; a < AA; a++) {
        av += Hc[a * HH + t] * Icb[a];
        pv += Hcb[a] * Ic[a * CC + t];
    }
    v0[t] = av;
    p0[t] = pv;
    if (t == 0) {
        float s = 0.f;
        for (int a = 0; a < AA; a++) s += Hcb[a] * Icb[a];
        s0[0] = s;
    }
}

__global__ __launch_bounds__(256) void k_P(const float* __restrict__ Hc,
                                           const float* __restrict__ Ic,
                                           float* __restrict__ P) {
    int k = blockIdx.y;
    int c = blockIdx.x * 256 + threadIdx.x;
    float acc = 0.f;
    for (int a = 0; a < AA; a++) acc += Hc[a * HH + k] * Ic[a * CC + c];
    P[k * CC + c] = acc;
}

__global__ __launch_bounds__(256) void k_G(const float* __restrict__ Wih,
                                           const float* __restrict__ Ic,
                                           float* __restrict__ Gtmp) {
    int gb = blockIdx.y * 8;
    int c = blockIdx.x * 256 + threadIdx.x;
    float acc[8];
#pragma unroll
    for (int j = 0; j < 8; j++) acc[j] = 0.f;
    for (int a = 0; a < AA; a++) {
        float ic = Ic[a * CC + c];
#pragma unroll
        for (int j = 0; j < 8; j++) acc[j] += Wih[(size_t)(gb + j) * VA + VV + a] * ic;
    }
#pragma unroll
    for (int j = 0; j < 8; j++) Gtmp[(size_t)(gb + j) * CC + c] = acc[j];
}

__global__ void k_gate_bias(const float* __restrict__ Wih, const float* __restrict__ Icb,
                            const float* __restrict__ bih, const float* __restrict__ bhh,
                            float* __restrict__ gate_bias) {
    int g = blockIdx.x * 256 + threadIdx.x;
    float acc = bih[g] + bhh[g];
    for (int a = 0; a < AA; a++) acc += Wih[(size_t)g * VA + VV + a] * Icb[a];
    gate_bias[g] = acc;
}

__global__ void k_transpose(const float* __restrict__ src, float* __restrict__ dst,
                            int R, int Cc, int ld, int col0) {
    __shared__ float tile[32][33];
    int r0 = blockIdx.y * 32, c0 = blockIdx.x * 32;
    int tx = threadIdx.x, ty = threadIdx.y;  // 32 x 8
#pragma unroll
    for (int k = 0; k < 4; k++) {
        int r = r0 + ty + k * 8, c = c0 + tx;
        if (r < R && c < Cc) tile[ty + k * 8][tx] = src[(size_t)r * ld + col0 + c];
    }
    __syncthreads();
#pragma unroll
    for (int k = 0; k < 4; k++) {
        int c = c0 + ty + k * 8, r = r0 + tx;
        if (c < Cc && r < R) dst[(size_t)c * R + r] = tile[tx][ty + k * 8];
    }
}

__global__ void k_init(const int* __restrict__ labels, float* __restrict__ h,
                       float* __restrict__ cst, int* __restrict__ charr) {
    int b = blockIdx.x, t = threadIdx.x;  // 64 x 512
    h[b * HH + t] = 0.f;
    cst[b * HH + t] = 0.f;
    if (t == 0) charr[b] = labels[b * TT];
}

// ---------------------------------------------------------------------------
// Persistent cooperative decode kernel: 256 blocks x 512 threads
// ---------------------------------------------------------------------------

struct KP {
    const float* X;      // [64,1024,512]
    const float* p0;     // [512]
    const float* v0;     // [512]
    const float* s0;     // [1]
    const float* P;      // [512 k][512 c]
    const float* GT;     // [512 c][2048 g]
    const float* WhhT;   // [512 c][2048 g]
    const float* Wih0T;  // [140 v][2048 g]
    const float* gateb;  // [2048]
    const float* Wout;   // [140,512]
    const float* bout;   // [140]
    float* h;            // [64,512]
    float* cst;          // [64,512]
    float* part_m;       // [64*4]
    float* part_l;       // [64*4]
    float* part_acc;     // [64*4,512]
    float* pg;           // [8,64,2048]
    float* qpart;        // [64*4,512]
    float* qbpart;       // [64*4]
    float* lpart;        // [64*4,LP]
    int* charr;          // [64]
    float* out;          // [64,128,140]
};

__global__ __launch_bounds__(512, 2) void k_decode(KP p) {
    cg::grid_group grid = cg::this_grid();
    const int bid = blockIdx.x, tid = threadIdx.x;
    const int w = tid >> 6, lane = tid & 63;
    const float inv_sqrt_a = 0.044194173824159216f;  // 1/sqrt(512)

    __shared__ union {
        struct { float lacc[8][512]; float lm[8]; float ll[8]; float logl[VV]; } p1;
        struct { float coefL[16][4]; float actT[2048]; float wbuf[8192]; } p2;
        struct { float gl[512]; float hl[128]; } p3;
    } sm;

    for (int t = 0; t < TT; t++) {
        // ================= P1: combine (t-1) + flash ========================
        {
            int b = bid >> 2, chunk = bid & 3;

            // ---- logits combine + argmax + out-write for step t-1 ----
            if (t > 0 && chunk == 0) {
                if (tid < VV) {
                    float lv = p.bout[tid];
#pragma unroll
                    for (int q = 0; q < 4; q++) lv += p.lpart[(b * 4 + q) * LP + tid];
                    sm.p1.logl[tid] = lv;
                    p.out[((size_t)b * TT + (t - 1)) * VV + tid] = lv;
                }
                __syncthreads();
                if (w == 0) {
                    float bv = -INFINITY;
                    int bi = 0x7fffffff;
#pragma unroll
                    for (int k = 0; k < 3; k++) {
                        int v = lane + (k << 6);
                        if (v < VV) {
                            float x = sm.p1.logl[v];
                            if (x > bv) { bv = x; bi = v; }
                        }
                    }
#pragma unroll
                    for (int off = 1; off < 64; off <<= 1) {
                        float ov = __shfl_xor(bv, off, 64);
                        int oi = __shfl_xor(bi, off, 64);
                        if (ov > bv || (ov == bv && oi < bi)) { bv = ov; bi = oi; }
                    }
                    if (lane == 0) p.charr[b] = bi;
                }
            }

            // ---- build q (each lane holds features lane*8..+8) ----
            float qv[8];
            {
                const float4* pp = (const float4*)p.p0 + lane * 2;
                float4 A = pp[0], B = pp[1];
                qv[0] = A.x; qv[1] = A.y; qv[2] = A.z; qv[3] = A.w;
                qv[4] = B.x; qv[5] = B.y; qv[6] = B.z; qv[7] = B.w;
            }
            float qoff = p.s0[0];
            if (t > 0) {
#pragma unroll
                for (int q = 0; q < 4; q++) {
                    const float4* qp4 = (const float4*)(p.qpart + (b * 4 + q) * 512) + lane * 2;
                    float4 A = qp4[0], B = qp4[1];
                    qv[0] += A.x; qv[1] += A.y; qv[2] += A.z; qv[3] += A.w;
                    qv[4] += B.x; qv[5] += B.y; qv[6] += B.z; qv[7] += B.w;
                    qoff += p.qbpart[b * 4 + q];
                }
            }

            // ---- flash over 256 rows, 32 per wave, ILP-4 groups ----
            float m = -INFINITY, l = 0.f;
            float acc[8];
#pragma unroll
            for (int j = 0; j < 8; j++) acc[j] = 0.f;

            int base = chunk * 256 + w * 32;
#pragma unroll 2
            for (int g = 0; g < 8; g++) {
                const float4* xp = (const float4*)(p.X + ((size_t)b * SS + base + g * 4) * CC) + lane * 2;
                float4 a0 = xp[0],   b0 = xp[1];
                float4 a1 = xp[128], b1 = xp[129];
                float4 a2 = xp[256], b2 = xp[257];
                float4 a3 = xp[384], b3 = xp[385];
                float d0 = a0.x * qv[0] + a0.y * qv[1] + a0.z * qv[2] + a0.w * qv[3] +
                           b0.x * qv[4] + b0.y * qv[5] + b0.z * qv[6] + b0.w * qv[7];
                float d1 = a1.x * qv[0] + a1.y * qv[1] + a1.z * qv[2] + a1.w * qv[3] +
                           b1.x * qv[4] + b1.y * qv[5] + b1.z * qv[6] + b1.w * qv[7];
                float d2 = a2.x * qv[0] + a2.y * qv[1] + a2.z * qv[2] + a2.w * qv[3] +
                           b2.x * qv[4] + b2.y * qv[5] + b2.z * qv[6] + b2.w * qv[7];
                float d3 = a3.x * qv[0] + a3.y * qv[1] + a3.z * qv[2] + a3.w * qv[3] +
                           b3.x * qv[4] + b3.y * qv[5] + b3.z * qv[6] + b3.w * qv[7];
#pragma unroll
                for (int off = 1; off < 64; off <<= 1) {
                    d0 += __shfl_xor(d0, off, 64);
                    d1 += __shfl_xor(d1, off, 64);
                    d2 += __shfl_xor(d2, off, 64);
                    d3 += __shfl_xor(d3, off, 64);
                }
                float sc0 = (d0 + qoff) * inv_sqrt_a;
                float sc1 = (d1 + qoff) * inv_sqrt_a;
                float sc2 = (d2 + qoff) * inv_sqrt_a;
                float sc3 = (d3 + qoff) * inv_sqrt_a;
                float mn = fmaxf(fmaxf(fmaxf(sc0, sc1), fmaxf(sc2, sc3)), m);
                float f = expf(m - mn);  // m=-inf first group -> 0
                float e0 = expf(sc0 - mn), e1 = expf(sc1 - mn);
                float e2 = expf(sc2 - mn), e3 = expf(sc3 - mn);
                l = l * f + (e0 + e1) + (e2 + e3);
                acc[0] = acc[0] * f + e0 * a0.x + e1 * a1.x + e2 * a2.x + e3 * a3.x;
                acc[1] = acc[1] * f + e0 * a0.y + e1 * a1.y + e2 * a2.y + e3 * a3.y;
                acc[2] = acc[2] * f + e0 * a0.z + e1 * a1.z + e2 * a2.z + e3 * a3.z;
                acc[3] = acc[3] * f + e0 * a0.w + e1 * a1.w + e2 * a2.w + e3 * a3.w;
                acc[4] = acc[4] * f + e0 * b0.x + e1 * b1.x + e2 * b2.x + e3 * b3.x;
                acc[5] = acc[5] * f + e0 * b0.y + e1 * b1.y + e2 * b2.y + e3 * b3.y;
                acc[6] = acc[6] * f + e0 * b0.z + e1 * b1.z + e2 * b2.z + e3 * b3.z;
                acc[7] = acc[7] * f + e0 * b0.w + e1 * b1.w + e2 * b2.w + e3 * b3.w;
                m = mn;
            }

            // ---- combine 8 waves -> block partial ----
            __syncthreads();  // logl (t-1) fully consumed before lacc reuse
            if (lane == 0) sm.p1.lm[w] = m;
            __syncthreads();
            float M = sm.p1.lm[0];
#pragma unroll
            for (int j = 1; j < 8; j++) M = fmaxf(M, sm.p1.lm[j]);
            float f = expf(m - M);
            if (lane == 0) sm.p1.ll[w] = l * f;
#pragma unroll
            for (int j = 0; j < 8; j++) sm.p1.lacc[w][lane * 8 + j] = acc[j] * f;
            __syncthreads();
            float s = 0.f;
#pragma unroll
            for (int j = 0; j < 8; j++) s += sm.p1.lacc[j][tid];
            p.part_acc[((b * 4 + chunk) << 9) + tid] = s;
            if (tid == 0) {
                float lt = 0.f;
                for (int j = 0; j < 8; j++) lt += sm.p1.ll[j];
                p.part_m[b * 4 + chunk] = M;
                p.part_l[b * 4 + chunk] = lt;
            }
        }
        grid.sync();

        // ================= P2: gates GEMM -> pg partials ====================
        {
            int cs = bid & 7, gt = (bid >> 3) & 7, bt = bid >> 6;
            int tg = tid & 63, tb = tid >> 6;  // tb = wave index (8), 2 b each

            if (cs < 4 && tid < 16) {
                int b = bt * 16 + tid;
                float m0 = p.part_m[b * 4 + 0], m1 = p.part_m[b * 4 + 1];
                float m2 = p.part_m[b * 4 + 2], m3 = p.part_m[b * 4 + 3];
                float M = fmaxf(fmaxf(m0, m1), fmaxf(m2, m3));
                float e0 = expf(m0 - M), e1 = expf(m1 - M);
                float e2 = expf(m2 - M), e3 = expf(m3 - M);
                float denom = e0 * p.part_l[b * 4 + 0] + e1 * p.part_l[b * 4 + 1] +
                              e2 * p.part_l[b * 4 + 2] + e3 * p.part_l[b * 4 + 3];
                float inv = 1.f / denom;
                sm.p2.coefL[tid][0] = e0 * inv; sm.p2.coefL[tid][1] = e1 * inv;
                sm.p2.coefL[tid][2] = e2 * inv; sm.p2.coefL[tid][3] = e3 * inv;
            }
            __syncthreads();
            if (cs < 4) {
#pragma unroll
                for (int k = 0; k < 4; k++) {
                    int idx = k * 512 + tid;
                    int bb = idx >> 7, cc = idx & 127;
                    const float* pa = p.part_acc + (size_t)((bt * 16 + bb) * 4) * 512 + cs * 128 + cc;
                    sm.p2.actT[cc * 16 + bb] =
                        sm.p2.coefL[bb][0] * pa[0] + sm.p2.coefL[bb][1] * pa[512] +
                        sm.p2.coefL[bb][2] * pa[1024] + sm.p2.coefL[bb][3] * pa[1536];
                }
            } else {
#pragma unroll
                for (int k = 0; k < 4; k++) {
                    int idx = k * 512 + tid;
                    int bb = idx >> 7, cc = idx & 127;
                    sm.p2.actT[cc * 16 + bb] = p.h[(bt * 16 + bb) * HH + (cs - 4) * 128 + cc];
                }
            }

            const float* W = (cs < 4) ? (p.GT + (size_t)(cs * 128) * G4)
                                      : (p.WhhT + (size_t)((cs - 4) * 128) * G4);
            float4 acc0 = make_float4(0, 0, 0, 0), acc1 = make_float4(0, 0, 0, 0);
            for (int cchunk = 0; cchunk < 4; cchunk++) {
                __syncthreads();
#pragma unroll
                for (int k = 0; k < 16; k++) {
                    int idx = k * 512 + tid;
                    int i = idx >> 8, j = idx & 255;
                    sm.p2.wbuf[idx] = W[(size_t)(cchunk * 32 + i) * G4 + gt * 256 + j];
                }
                __syncthreads();
#pragma unroll 8
                for (int i = 0; i < 32; i++) {
                    float4 wv = *(const float4*)&sm.p2.wbuf[i * 256 + tg * 4];
                    float2 av = *(const float2*)&sm.p2.actT[(cchunk * 32 + i) * 16 + tb * 2];
                    acc0.x += av.x * wv.x; acc0.y += av.x * wv.y;
                    acc0.z += av.x * wv.z; acc0.w += av.x * wv.w;
                    acc1.x += av.y * wv.x; acc1.y += av.y * wv.y;
                    acc1.z += av.y * wv.z; acc1.w += av.y * wv.w;
                }
            }
            int b0 = bt * 16 + tb * 2;
            int g0 = gt * 256 + tg * 4;
            *(float4*)&p.pg[(size_t)(cs * BB + b0) * G4 + g0] = acc0;
            *(float4*)&p.pg[(size_t)(cs * BB + b0 + 1) * G4 + g0] = acc1;
        }
        grid.sync();

        // ======== P3: gate sum + LSTM + logits/q'/qb partials ==============
        {
            int b = bid >> 2, q = bid & 3;
            int ch = p.charr[b];

            int gcls = tid >> 7, nloc = tid & 127;
            int gidx = gcls * 512 + q * 128 + nloc;
            float a = p.gateb[gidx] + p.Wih0T[(size_t)ch * G4 + gidx];
#pragma unroll
            for (int j = 0; j < 8; j++) a += p.pg[(size_t)(j * BB + b) * G4 + gidx];
            sm.p3.gl[tid] = a;
            __syncthreads();

            if (tid < 128) {
                float ig = 1.f / (1.f + expf(-sm.p3.gl[tid]));
                float fg = 1.f / (1.f + expf(-sm.p3.gl[128 + tid]));
                float gg = tanhf(sm.p3.gl[256 + tid]);
                float og = 1.f / (1.f + expf(-sm.p3.gl[384 + tid]));
                int n = q * 128 + tid;
                float cv = p.cst[b * HH + n];
                float cn = fg * cv + ig * gg;
                float hn = og * tanhf(cn);
                p.cst[b * HH + n] = cn;
                p.h[b * HH + n] = hn;
                sm.p3.hl[tid] = hn;
            }
            __syncthreads();

            // logits partials over this quarter's 128 h dims
            {
                int n2 = lane * 2;
                float h0 = sm.p3.hl[n2], h1 = sm.p3.hl[n2 + 1];
                for (int v = w; v < VV; v += 8) {
                    float2 w2 = *(const float2*)&p.Wout[(size_t)v * HH + q * 128 + n2];
                    float d = h0 * w2.x + h1 * w2.y;
#pragma unroll
                    for (int off = 1; off < 64; off <<= 1) d += __shfl_xor(d, off, 64);
                    if (lane == 0) p.lpart[(b * 4 + q) * LP + v] = d;
                }
            }

            // q' partial: qpart[b][q][c] = sum_{n in slice} h[n] * P[n][c]
            {
                float a2 = 0.f;
                const float* Pr = p.P + (size_t)(q * 128) * CC + tid;
#pragma unroll 4
                for (int j = 0; j < 128; j++) a2 += sm.p3.hl[j] * Pr[(size_t)j * CC];
                p.qpart[(b * 4 + q) * 512 + tid] = a2;
            }

            // qb partial
            if (w == 0) {
                int n2 = lane * 2;
                float pr = sm.p3.hl[n2] * p.v0[q * 128 + n2] +
                           sm.p3.hl[n2 + 1] * p.v0[q * 128 + n2 + 1];
#pragma unroll
                for (int off = 1; off < 64; off <<= 1) pr += __shfl_xor(pr, off, 64);
                if (lane == 0) p.qbpart[b * 4 + q] = pr;
            }
        }
        grid.sync();
    }

    // final logits combine for t = 127
    {
        int b = bid >> 2, chunk = bid & 3;
        if (chunk == 0 && tid < VV) {
            float lv = p.bout[tid];
#pragma unroll
            for (int q = 0; q < 4; q++) lv += p.lpart[(b * 4 + q) * LP + tid];
            p.out[((size_t)b * TT + (TT - 1)) * VV + tid] = lv;
        }
    }
}

// ---------------------------------------------------------------------------

extern "C" void kernel_launch(void* const* d_in, const int* in_sizes, int n_in,
                              void* d_out, int out_size, void* d_ws, size_t ws_size,
                              hipStream_t stream) {
    const float* X    = (const float*)d_in[0];   // [64,1024,512]
    const int*   lab  = (const int*)d_in[1];     // [64,128]
    const float* Icw  = (const float*)d_in[2];   // [512,512]
    const float* Icb  = (const float*)d_in[3];   // [512]
    const float* Hcw  = (const float*)d_in[4];   // [512,512]
    const float* Hcb  = (const float*)d_in[5];   // [512]
    const float* Wih  = (const float*)d_in[6];   // [2048,652]
    const float* bih  = (const float*)d_in[7];   // [2048]
    const float* Whh  = (const float*)d_in[8];   // [2048,512]
    const float* bhh  = (const float*)d_in[9];   // [2048]
    const float* Wout = (const float*)d_in[10];  // [140,512]
    const float* bout = (const float*)d_in[11];  // [140]
    float* out = (float*)d_out;                  // [64,128,140]

    float* ws = (float*)d_ws;
    size_t off = 0;
    float* P        = ws + off; off += 512 * 512;
    float* GT       = ws + off; off += 512 * 2048;
    float* WhhT     = ws + off; off += 512 * 2048;
    float* Wih0T    = ws + off; off += 140 * 2048;
    float* gateb    = ws + off; off += 2048;
    float* p0       = ws + off; off += 512;
    float* v0       = ws + off; off += 512;
    float* s0       = ws + off; off += 64;
    float* h        = ws + off; off += 64 * 512;
    float* cst      = ws + off; off += 64 * 512;
    float* part_m   = ws + off; off += 256;
    float* part_l   = ws + off; off += 256;
    float* part_acc = ws + off; off += 64 * 4 * 512;
    float* pg       = ws + off; off += 8 * 64 * 2048;
    float* qpart    = ws + off; off += 64 * 4 * 512;
    float* qbpart   = ws + off; off += 256;
    float* lpart    = ws + off; off += 64 * 4 * LP;   // FIX: was 64*LP (OOB fault)
    int*   charr    = (int*)(ws + off); off += 64;
    if (ws_size < off * sizeof(float)) return;

    float* Gtmp = pg;  // pg only live after first P2; reuse for precompute

    k_small<<<1, 512, 0, stream>>>(Hcw, Hcb, Icw, Icb, p0, v0, s0);
    k_P<<<dim3(2, 512), 256, 0, stream>>>(Hcw, Icw, P);
    k_G<<<dim3(2, 256), 256, 0, stream>>>(Wih, Icw, Gtmp);
    k_transpose<<<dim3(16, 64), dim3(32, 8), 0, stream>>>(Gtmp, GT, 2048, 512, 512, 0);
    k_transpose<<<dim3(16, 64), dim3(32, 8), 0, stream>>>(Whh, WhhT, 2048, 512, 512, 0);
    k_transpose<<<dim3(5, 64), dim3(32, 8), 0, stream>>>(Wih, Wih0T, 2048, 140, 652, 0);
    k_gate_bias<<<8, 256, 0, stream>>>(Wih, Icb, bih, bhh, gateb);
    k_init<<<64, 512, 0, stream>>>(lab, h, cst, charr);

    KP kp;
    kp.X = X; kp.p0 = p0; kp.v0 = v0; kp.s0 = s0; kp.P = P;
    kp.GT = GT; kp.WhhT = WhhT; kp.Wih0T = Wih0T; kp.gateb = gateb;
    kp.Wout = Wout; kp.bout = bout;
    kp.h = h; kp.cst = cst; kp.part_m = part_m; kp.part_l = part_l;
    kp.part_acc = part_acc; kp.pg = pg; kp.qpart = qpart; kp.qbpart = qbpart;
    kp.lpart = lpart; kp.charr = charr; kp.out = out;

    void* args[] = { &kp };
    hipLaunchCooperativeKernel((const void*)k_decode, dim3(256), dim3(512),
                               args, 0, stream);
}

// Round 4
// 16586.922 us; speedup vs baseline: 1.1464x; 1.1464x over previous
//
#include <hip/hip_runtime.h>
#include <math.h>

#define BB 64
#define SS 1024
#define CC 512
#define VV 140
#define AA 512
#define HH 512
#define TT 128
#define G4 2048   // 4*H
#define VA 652    // V+A
#define LP 144    // lpart stride (140 padded)

// ---------------------------------------------------------------------------
// One-time precompute kernels
// ---------------------------------------------------------------------------

__global__ void k_small(const float* __restrict__ Hc, const float* __restrict__ Hcb,
                        const float* __restrict__ Ic, const float* __restrict__ Icb,
                        float* __restrict__ p0, float* __restrict__ v0,
                        float* __restrict__ s0) {
    int t = threadIdx.x;  // 512
    float av = 0.f, pv = 0.f;
    for (int a = 0; a < AA; a++) {
        av += Hc[a * HH + t] * Icb[a];
        pv += Hcb[a] * Ic[a * CC + t];
    }
    v0[t] = av;
    p0[t] = pv;
    if (t == 0) {
        float s = 0.f;
        for (int a = 0; a < AA; a++) s += Hcb[a] * Icb[a];
        s0[0] = s;
    }
}

__global__ __launch_bounds__(256) void k_P(const float* __restrict__ Hc,
                                           const float* __restrict__ Ic,
                                           float* __restrict__ P) {
    int k = blockIdx.y;
    int c = blockIdx.x * 256 + threadIdx.x;
    float acc = 0.f;
    for (int a = 0; a < AA; a++) acc += Hc[a * HH + k] * Ic[a * CC + c];
    P[k * CC + c] = acc;
}

__global__ __launch_bounds__(256) void k_G(const float* __restrict__ Wih,
                                           const float* __restrict__ Ic,
                                           float* __restrict__ Gtmp) {
    int gb = blockIdx.y * 8;
    int c = blockIdx.x * 256 + threadIdx.x;
    float acc[8];
#pragma unroll
    for (int j = 0; j < 8; j++) acc[j] = 0.f;
    for (int a = 0; a < AA; a++) {
        float ic = Ic[a * CC + c];
#pragma unroll
        for (int j = 0; j < 8; j++) acc[j] += Wih[(size_t)(gb + j) * VA + VV + a] * ic;
    }
#pragma unroll
    for (int j = 0; j < 8; j++) Gtmp[(size_t)(gb + j) * CC + c] = acc[j];
}

__global__ void k_gate_bias(const float* __restrict__ Wih, const float* __restrict__ Icb,
                            const float* __restrict__ bih, const float* __restrict__ bhh,
                            float* __restrict__ gate_bias) {
    int g = blockIdx.x * 256 + threadIdx.x;
    float acc = bih[g] + bhh[g];
    for (int a = 0; a < AA; a++) acc += Wih[(size_t)g * VA + VV + a] * Icb[a];
    gate_bias[g] = acc;
}

__global__ void k_transpose(const float* __restrict__ src, float* __restrict__ dst,
                            int R, int Cc, int ld, int col0) {
    __shared__ float tile[32][33];
    int r0 = blockIdx.y * 32, c0 = blockIdx.x * 32;
    int tx = threadIdx.x, ty = threadIdx.y;  // 32 x 8
#pragma unroll
    for (int k = 0; k < 4; k++) {
        int r = r0 + ty + k * 8, c = c0 + tx;
        if (r < R && c < Cc) tile[ty + k * 8][tx] = src[(size_t)r * ld + col0 + c];
    }
    __syncthreads();
#pragma unroll
    for (int k = 0; k < 4; k++) {
        int c = c0 + ty + k * 8, r = r0 + tx;
        if (c < Cc && r < R) dst[(size_t)c * R + r] = tile[tx][ty + k * 8];
    }
}

__global__ void k_init(const int* __restrict__ labels, float* __restrict__ h,
                       float* __restrict__ cst, int* __restrict__ charr,
                       unsigned int* __restrict__ bar) {
    int b = blockIdx.x, t = threadIdx.x;  // 64 x 512
    h[b * HH + t] = 0.f;
    cst[b * HH + t] = 0.f;
    if (t == 0) charr[b] = labels[b * TT];
    if (b == 0 && t == 0) bar[0] = 0u;  // barrier counter (ws is 0xAA-poisoned)
}

// ---------------------------------------------------------------------------
// Lightweight grid barrier: monotonic counter, agent-scope atomics.
// Protocol matches what cg::grid.sync does (threadfence + atomic + spin),
// which round-3 proved correct cross-XCD on this chip — minus its overhead.
// ---------------------------------------------------------------------------
__device__ __forceinline__ void gridbar(unsigned int* bar, unsigned int target) {
    __syncthreads();
    if (threadIdx.x == 0) {
        __threadfence();  // release this block's global writes (agent scope)
        __hip_atomic_fetch_add(bar, 1u, __ATOMIC_ACQ_REL, __HIP_MEMORY_SCOPE_AGENT);
        while (__hip_atomic_load(bar, __ATOMIC_ACQUIRE, __HIP_MEMORY_SCOPE_AGENT) < target) {
            __builtin_amdgcn_s_sleep(8);
        }
        __threadfence();  // acquire other blocks' writes
    }
    __syncthreads();
}

// ---------------------------------------------------------------------------
// Persistent decode kernel: 256 blocks x 512 threads (1 block/CU)
// ---------------------------------------------------------------------------

struct KP {
    const float* X;      // [64,1024,512]
    const float* p0;     // [512]
    const float* v0;     // [512]
    const float* s0;     // [1]
    const float* P;      // [512 k][512 c]
    const float* GT;     // [512 c][2048 g]
    const float* WhhT;   // [512 c][2048 g]
    const float* Wih0T;  // [140 v][2048 g]
    const float* gateb;  // [2048]
    const float* Wout;   // [140,512]
    const float* bout;   // [140]
    float* h;            // [64,512]
    float* cst;          // [64,512]
    float* part_m;       // [64*4]
    float* part_l;       // [64*4]
    float* part_acc;     // [64*4,512]
    float* pg;           // [8,64,2048]
    float* qpart;        // [64*4,512]
    float* qbpart;       // [64*4]
    float* lpart;        // [64*4,LP]
    int* charr;          // [64]
    unsigned int* bar;   // [1] grid barrier
    float* out;          // [64,128,140]
};

__global__ __launch_bounds__(512, 2) void k_decode(KP p) {
    const int bid = blockIdx.x, tid = threadIdx.x;
    const int w = tid >> 6, lane = tid & 63;
    const float inv_sqrt_a = 0.044194173824159216f;  // 1/sqrt(512)
    unsigned int ep = 0;

    __shared__ union {
        struct { float lacc[8][512]; float lm[8]; float ll[8]; float logl[VV]; } p1;
        struct { float coefL[16][4]; float actT[2048]; float wbuf[8192]; } p2;
        struct { float gl[512]; float hl[128]; } p3;
    } sm;

    for (int t = 0; t < TT; t++) {
        // ================= P1: combine (t-1) + flash ========================
        {
            int b = bid >> 2, chunk = bid & 3;

            // ---- logits combine + argmax + out-write for step t-1 ----
            if (t > 0 && chunk == 0) {
                if (tid < VV) {
                    float lv = p.bout[tid];
#pragma unroll
                    for (int q = 0; q < 4; q++) lv += p.lpart[(b * 4 + q) * LP + tid];
                    sm.p1.logl[tid] = lv;
                    p.out[((size_t)b * TT + (t - 1)) * VV + tid] = lv;
                }
                __syncthreads();
                if (w == 0) {
                    float bv = -INFINITY;
                    int bi = 0x7fffffff;
#pragma unroll
                    for (int k = 0; k < 3; k++) {
                        int v = lane + (k << 6);
                        if (v < VV) {
                            float x = sm.p1.logl[v];
                            if (x > bv) { bv = x; bi = v; }
                        }
                    }
#pragma unroll
                    for (int off = 1; off < 64; off <<= 1) {
                        float ov = __shfl_xor(bv, off, 64);
                        int oi = __shfl_xor(bi, off, 64);
                        if (ov > bv || (ov == bv && oi < bi)) { bv = ov; bi = oi; }
                    }
                    if (lane == 0) p.charr[b] = bi;
                }
            }

            // ---- build q (each lane holds features lane*8..+8) ----
            float qv[8];
            {
                const float4* pp = (const float4*)p.p0 + lane * 2;
                float4 A = pp[0], B = pp[1];
                qv[0] = A.x; qv[1] = A.y; qv[2] = A.z; qv[3] = A.w;
                qv[4] = B.x; qv[5] = B.y; qv[6] = B.z; qv[7] = B.w;
            }
            float qoff = p.s0[0];
            if (t > 0) {
#pragma unroll
                for (int q = 0; q < 4; q++) {
                    const float4* qp4 = (const float4*)(p.qpart + (b * 4 + q) * 512) + lane * 2;
                    float4 A = qp4[0], B = qp4[1];
                    qv[0] += A.x; qv[1] += A.y; qv[2] += A.z; qv[3] += A.w;
                    qv[4] += B.x; qv[5] += B.y; qv[6] += B.z; qv[7] += B.w;
                    qoff += p.qbpart[b * 4 + q];
                }
            }

            // ---- flash over 256 rows, 32 per wave, ILP-4 groups ----
            float m = -INFINITY, l = 0.f;
            float acc[8];
#pragma unroll
            for (int j = 0; j < 8; j++) acc[j] = 0.f;

            int base = chunk * 256 + w * 32;
#pragma unroll 2
            for (int g = 0; g < 8; g++) {
                const float4* xp = (const float4*)(p.X + ((size_t)b * SS + base + g * 4) * CC) + lane * 2;
                float4 a0 = xp[0],   b0 = xp[1];
                float4 a1 = xp[128], b1 = xp[129];
                float4 a2 = xp[256], b2 = xp[257];
                float4 a3 = xp[384], b3 = xp[385];
                float d0 = a0.x * qv[0] + a0.y * qv[1] + a0.z * qv[2] + a0.w * qv[3] +
                           b0.x * qv[4] + b0.y * qv[5] + b0.z * qv[6] + b0.w * qv[7];
                float d1 = a1.x * qv[0] + a1.y * qv[1] + a1.z * qv[2] + a1.w * qv[3] +
                           b1.x * qv[4] + b1.y * qv[5] + b1.z * qv[6] + b1.w * qv[7];
                float d2 = a2.x * qv[0] + a2.y * qv[1] + a2.z * qv[2] + a2.w * qv[3] +
                           b2.x * qv[4] + b2.y * qv[5] + b2.z * qv[6] + b2.w * qv[7];
                float d3 = a3.x * qv[0] + a3.y * qv[1] + a3.z * qv[2] + a3.w * qv[3] +
                           b3.x * qv[4] + b3.y * qv[5] + b3.z * qv[6] + b3.w * qv[7];
#pragma unroll
                for (int off = 1; off < 64; off <<= 1) {
                    d0 += __shfl_xor(d0, off, 64);
                    d1 += __shfl_xor(d1, off, 64);
                    d2 += __shfl_xor(d2, off, 64);
                    d3 += __shfl_xor(d3, off, 64);
                }
                float sc0 = (d0 + qoff) * inv_sqrt_a;
                float sc1 = (d1 + qoff) * inv_sqrt_a;
                float sc2 = (d2 + qoff) * inv_sqrt_a;
                float sc3 = (d3 + qoff) * inv_sqrt_a;
                float mn = fmaxf(fmaxf(fmaxf(sc0, sc1), fmaxf(sc2, sc3)), m);
                float f = expf(m - mn);  // m=-inf first group -> 0
                float e0 = expf(sc0 - mn), e1 = expf(sc1 - mn);
                float e2 = expf(sc2 - mn), e3 = expf(sc3 - mn);
                l = l * f + (e0 + e1) + (e2 + e3);
                acc[0] = acc[0] * f + e0 * a0.x + e1 * a1.x + e2 * a2.x + e3 * a3.x;
                acc[1] = acc[1] * f + e0 * a0.y + e1 * a1.y + e2 * a2.y + e3 * a3.y;
                acc[2] = acc[2] * f + e0 * a0.z + e1 * a1.z + e2 * a2.z + e3 * a3.z;
                acc[3] = acc[3] * f + e0 * a0.w + e1 * a1.w + e2 * a2.w + e3 * a3.w;
                acc[4] = acc[4] * f + e0 * b0.x + e1 * b1.x + e2 * b2.x + e3 * b3.x;
                acc[5] = acc[5] * f + e0 * b0.y + e1 * b1.y + e2 * b2.y + e3 * b3.y;
                acc[6] = acc[6] * f + e0 * b0.z + e1 * b1.z + e2 * b2.z + e3 * b3.z;
                acc[7] = acc[7] * f + e0 * b0.w + e1 * b1.w + e2 * b2.w + e3 * b3.w;
                m = mn;
            }

            // ---- combine 8 waves -> block partial ----
            // layout: lacc[w][j*64+lane] (stride-1 writes, conflict-free;
            // read side pays a cheap one-shot 8-way)
            __syncthreads();  // logl (t-1) fully consumed before lacc reuse
            if (lane == 0) sm.p1.lm[w] = m;
            __syncthreads();
            float M = sm.p1.lm[0];
#pragma unroll
            for (int j = 1; j < 8; j++) M = fmaxf(M, sm.p1.lm[j]);
            float f = expf(m - M);
            if (lane == 0) sm.p1.ll[w] = l * f;
#pragma unroll
            for (int j = 0; j < 8; j++) sm.p1.lacc[w][j * 64 + lane] = acc[j] * f;
            __syncthreads();
            {
                int ridx = (tid & 7) * 64 + (tid >> 3);  // element c=tid lives here
                float s = 0.f;
#pragma unroll
                for (int j = 0; j < 8; j++) s += sm.p1.lacc[j][ridx];
                p.part_acc[((b * 4 + chunk) << 9) + tid] = s;
            }
            if (tid == 0) {
                float lt = 0.f;
                for (int j = 0; j < 8; j++) lt += sm.p1.ll[j];
                p.part_m[b * 4 + chunk] = M;
                p.part_l[b * 4 + chunk] = lt;
            }
        }
        gridbar(p.bar, (++ep) * 256u);

        // ================= P2: gates GEMM -> pg partials ====================
        {
            int cs = bid & 7, gt = (bid >> 3) & 7, bt = bid >> 6;
            int tg = tid & 63, tb = tid >> 6;  // tb = wave index (8), 2 b each

            if (cs < 4 && tid < 16) {
                int b = bt * 16 + tid;
                float m0 = p.part_m[b * 4 + 0], m1 = p.part_m[b * 4 + 1];
                float m2 = p.part_m[b * 4 + 2], m3 = p.part_m[b * 4 + 3];
                float M = fmaxf(fmaxf(m0, m1), fmaxf(m2, m3));
                float e0 = expf(m0 - M), e1 = expf(m1 - M);
                float e2 = expf(m2 - M), e3 = expf(m3 - M);
                float denom = e0 * p.part_l[b * 4 + 0] + e1 * p.part_l[b * 4 + 1] +
                              e2 * p.part_l[b * 4 + 2] + e3 * p.part_l[b * 4 + 3];
                float inv = 1.f / denom;
                sm.p2.coefL[tid][0] = e0 * inv; sm.p2.coefL[tid][1] = e1 * inv;
                sm.p2.coefL[tid][2] = e2 * inv; sm.p2.coefL[tid][3] = e3 * inv;
            }
            __syncthreads();
            // actT layout: [bb 16][cc 128] -> addr == idx (stride-1, conflict-free)
            if (cs < 4) {
#pragma unroll
                for (int k = 0; k < 4; k++) {
                    int idx = k * 512 + tid;
                    int bb = idx >> 7, cc = idx & 127;
                    const float* pa = p.part_acc + (size_t)((bt * 16 + bb) * 4) * 512 + cs * 128 + cc;
                    sm.p2.actT[idx] =
                        sm.p2.coefL[bb][0] * pa[0] + sm.p2.coefL[bb][1] * pa[512] +
                        sm.p2.coefL[bb][2] * pa[1024] + sm.p2.coefL[bb][3] * pa[1536];
                }
            } else {
#pragma unroll
                for (int k = 0; k < 4; k++) {
                    int idx = k * 512 + tid;
                    int bb = idx >> 7, cc = idx & 127;
                    sm.p2.actT[idx] = p.h[(bt * 16 + bb) * HH + (cs - 4) * 128 + cc];
                }
            }

            const float* W = (cs < 4) ? (p.GT + (size_t)(cs * 128) * G4)
                                      : (p.WhhT + (size_t)((cs - 4) * 128) * G4);
            float4 acc0 = make_float4(0, 0, 0, 0), acc1 = make_float4(0, 0, 0, 0);
            for (int cchunk = 0; cchunk < 4; cchunk++) {
                __syncthreads();
                {
                    const float4* Wr = (const float4*)(W + (size_t)(cchunk * 32) * G4 + gt * 256);
                    float4* wb4 = (float4*)sm.p2.wbuf;
#pragma unroll
                    for (int k = 0; k < 4; k++) {
                        int idx = k * 512 + tid;         // idx = i*64 + j4
                        int i = idx >> 6, j4 = idx & 63;
                        wb4[idx] = Wr[(size_t)i * (G4 / 4) + j4];
                    }
                }
                __syncthreads();
#pragma unroll 8
                for (int i = 0; i < 32; i++) {
                    float4 wv = *(const float4*)&sm.p2.wbuf[i * 256 + tg * 4];
                    float ax = sm.p2.actT[(tb * 2) * 128 + cchunk * 32 + i];
                    float ay = sm.p2.actT[(tb * 2 + 1) * 128 + cchunk * 32 + i];
                    acc0.x += ax * wv.x; acc0.y += ax * wv.y;
                    acc0.z += ax * wv.z; acc0.w += ax * wv.w;
                    acc1.x += ay * wv.x; acc1.y += ay * wv.y;
                    acc1.z += ay * wv.z; acc1.w += ay * wv.w;
                }
            }
            int b0 = bt * 16 + tb * 2;
            int g0 = gt * 256 + tg * 4;
            *(float4*)&p.pg[(size_t)(cs * BB + b0) * G4 + g0] = acc0;
            *(float4*)&p.pg[(size_t)(cs * BB + b0 + 1) * G4 + g0] = acc1;
        }
        gridbar(p.bar, (++ep) * 256u);

        // ======== P3: gate sum + LSTM + logits/q'/qb partials ==============
        {
            int b = bid >> 2, q = bid & 3;
            int ch = p.charr[b];

            int gcls = tid >> 7, nloc = tid & 127;
            int gidx = gcls * 512 + q * 128 + nloc;
            float a = p.gateb[gidx] + p.Wih0T[(size_t)ch * G4 + gidx];
#pragma unroll
            for (int j = 0; j < 8; j++) a += p.pg[(size_t)(j * BB + b) * G4 + gidx];
            sm.p3.gl[tid] = a;
            __syncthreads();

            if (tid < 128) {
                float ig = 1.f / (1.f + expf(-sm.p3.gl[tid]));
                float fg = 1.f / (1.f + expf(-sm.p3.gl[128 + tid]));
                float gg = tanhf(sm.p3.gl[256 + tid]);
                float og = 1.f / (1.f + expf(-sm.p3.gl[384 + tid]));
                int n = q * 128 + tid;
                float cv = p.cst[b * HH + n];
                float cn = fg * cv + ig * gg;
                float hn = og * tanhf(cn);
                p.cst[b * HH + n] = cn;
                p.h[b * HH + n] = hn;
                sm.p3.hl[tid] = hn;
            }
            __syncthreads();

            // logits partials over this quarter's 128 h dims
            {
                int n2 = lane * 2;
                float h0 = sm.p3.hl[n2], h1 = sm.p3.hl[n2 + 1];
                for (int v = w; v < VV; v += 8) {
                    float2 w2 = *(const float2*)&p.Wout[(size_t)v * HH + q * 128 + n2];
                    float d = h0 * w2.x + h1 * w2.y;
#pragma unroll
                    for (int off = 1; off < 64; off <<= 1) d += __shfl_xor(d, off, 64);
                    if (lane == 0) p.lpart[(b * 4 + q) * LP + v] = d;
                }
            }

            // q' partial: qpart[b][q][c] = sum_{n in slice} h[n] * P[n][c]
            {
                float a2 = 0.f;
                const float* Pr = p.P + (size_t)(q * 128) * CC + tid;
#pragma unroll 4
                for (int j = 0; j < 128; j++) a2 += sm.p3.hl[j] * Pr[(size_t)j * CC];
                p.qpart[(b * 4 + q) * 512 + tid] = a2;
            }

            // qb partial
            if (w == 0) {
                int n2 = lane * 2;
                float pr = sm.p3.hl[n2] * p.v0[q * 128 + n2] +
                           sm.p3.hl[n2 + 1] * p.v0[q * 128 + n2 + 1];
#pragma unroll
                for (int off = 1; off < 64; off <<= 1) pr += __shfl_xor(pr, off, 64);
                if (lane == 0) p.qbpart[b * 4 + q] = pr;
            }
        }
        gridbar(p.bar, (++ep) * 256u);
    }

    // final logits combine for t = 127
    {
        int b = bid >> 2, chunk = bid & 3;
        if (chunk == 0 && tid < VV) {
            float lv = p.bout[tid];
#pragma unroll
            for (int q = 0; q < 4; q++) lv += p.lpart[(b * 4 + q) * LP + tid];
            p.out[((size_t)b * TT + (TT - 1)) * VV + tid] = lv;
        }
    }
}

// ---------------------------------------------------------------------------

extern "C" void kernel_launch(void* const* d_in, const int* in_sizes, int n_in,
                              void* d_out, int out_size, void* d_ws, size_t ws_size,
                              hipStream_t stream) {
    const float* X    = (const float*)d_in[0];   // [64,1024,512]
    const int*   lab  = (const int*)d_in[1];     // [64,128]
    const float* Icw  = (const float*)d_in[2];   // [512,512]
    const float* Icb  = (const float*)d_in[3];   // [512]
    const float* Hcw  = (const float*)d_in[4];   // [512,512]
    const float* Hcb  = (const float*)d_in[5];   // [512]
    const float* Wih  = (const float*)d_in[6];   // [2048,652]
    const float* bih  = (const float*)d_in[7];   // [2048]
    const float* Whh  = (const float*)d_in[8];   // [2048,512]
    const float* bhh  = (const float*)d_in[9];   // [2048]
    const float* Wout = (const float*)d_in[10];  // [140,512]
    const float* bout = (const float*)d_in[11];  // [140]
    float* out = (float*)d_out;                  // [64,128,140]

    float* ws = (float*)d_ws;
    size_t off = 0;
    float* P        = ws + off; off += 512 * 512;
    float* GT       = ws + off; off += 512 * 2048;
    float* WhhT     = ws + off; off += 512 * 2048;
    float* Wih0T    = ws + off; off += 140 * 2048;
    float* gateb    = ws + off; off += 2048;
    float* p0       = ws + off; off += 512;
    float* v0       = ws + off; off += 512;
    float* s0       = ws + off; off += 64;
    float* h        = ws + off; off += 64 * 512;
    float* cst      = ws + off; off += 64 * 512;
    float* part_m   = ws + off; off += 256;
    float* part_l   = ws + off; off += 256;
    float* part_acc = ws + off; off += 64 * 4 * 512;
    float* pg       = ws + off; off += 8 * 64 * 2048;
    float* qpart    = ws + off; off += 64 * 4 * 512;
    float* qbpart   = ws + off; off += 256;
    float* lpart    = ws + off; off += 64 * 4 * LP;
    int*   charr    = (int*)(ws + off); off += 64;
    unsigned int* bar = (unsigned int*)(ws + off); off += 64;
    if (ws_size < off * sizeof(float)) return;

    float* Gtmp = pg;  // pg only live after first P2; reuse for precompute

    k_small<<<1, 512, 0, stream>>>(Hcw, Hcb, Icw, Icb, p0, v0, s0);
    k_P<<<dim3(2, 512), 256, 0, stream>>>(Hcw, Icw, P);
    k_G<<<dim3(2, 256), 256, 0, stream>>>(Wih, Icw, Gtmp);
    k_transpose<<<dim3(16, 64), dim3(32, 8), 0, stream>>>(Gtmp, GT, 2048, 512, 512, 0);
    k_transpose<<<dim3(16, 64), dim3(32, 8), 0, stream>>>(Whh, WhhT, 2048, 512, 512, 0);
    k_transpose<<<dim3(5, 64), dim3(32, 8), 0, stream>>>(Wih, Wih0T, 2048, 140, 652, 0);
    k_gate_bias<<<8, 256, 0, stream>>>(Wih, Icb, bih, bhh, gateb);
    k_init<<<64, 512, 0, stream>>>(lab, h, cst, charr, bar);

    KP kp;
    kp.X = X; kp.p0 = p0; kp.v0 = v0; kp.s0 = s0; kp.P = P;
    kp.GT = GT; kp.WhhT = WhhT; kp.Wih0T = Wih0T; kp.gateb = gateb;
    kp.Wout = Wout; kp.bout = bout;
    kp.h = h; kp.cst = cst; kp.part_m = part_m; kp.part_l = part_l;
    kp.part_acc = part_acc; kp.pg = pg; kp.qpart = qpart; kp.qbpart = qbpart;
    kp.lpart = lpart; kp.charr = charr; kp.bar = bar; kp.out = out;

    KP* kpp = &kp;
    void* args[] = { &kp };
    hipLaunchCooperativeKernel((const void*)k_decode, dim3(256), dim3(512),
                               args, 0, stream);
    (void)kpp;
}

// Round 5
// 13181.746 us; speedup vs baseline: 1.4426x; 1.2583x over previous
//
#include <hip/hip_runtime.h>
#include <math.h>

#define BB 64
#define SS 1024
#define CC 512
#define VV 140
#define AA 512
#define HH 512
#define TT 128
#define G4 2048   // 4*H
#define VA 652    // V+A
#define LP 144    // lpart stride (140 padded)
#define NFLAG 4096  // 256 flags x 16-uint (64B) stride

// ---------------------------------------------------------------------------
// One-time precompute kernels
// ---------------------------------------------------------------------------

__global__ void k_small(const float* __restrict__ Hc, const float* __restrict__ Hcb,
                        const float* __restrict__ Ic, const float* __restrict__ Icb,
                        float* __restrict__ p0, float* __restrict__ v0,
                        float* __restrict__ s0) {
    int t = threadIdx.x;  // 512
    float av = 0.f, pv = 0.f;
    for (int a = 0; a < AA; a++) {
        av += Hc[a * HH + t] * Icb[a];
        pv += Hcb[a] * Ic[a * CC + t];
    }
    v0[t] = av;
    p0[t] = pv;
    if (t == 0) {
        float s = 0.f;
        for (int a = 0; a < AA; a++) s += Hcb[a] * Icb[a];
        s0[0] = s;
    }
}

__global__ __launch_bounds__(256) void k_P(const float* __restrict__ Hc,
                                           const float* __restrict__ Ic,
                                           float* __restrict__ P) {
    int k = blockIdx.y;
    int c = blockIdx.x * 256 + threadIdx.x;
    float acc = 0.f;
    for (int a = 0; a < AA; a++) acc += Hc[a * HH + k] * Ic[a * CC + c];
    P[k * CC + c] = acc;
}

__global__ __launch_bounds__(256) void k_G(const float* __restrict__ Wih,
                                           const float* __restrict__ Ic,
                                           float* __restrict__ Gtmp) {
    int gb = blockIdx.y * 8;
    int c = blockIdx.x * 256 + threadIdx.x;
    float acc[8];
#pragma unroll
    for (int j = 0; j < 8; j++) acc[j] = 0.f;
    for (int a = 0; a < AA; a++) {
        float ic = Ic[a * CC + c];
#pragma unroll
        for (int j = 0; j < 8; j++) acc[j] += Wih[(size_t)(gb + j) * VA + VV + a] * ic;
    }
#pragma unroll
    for (int j = 0; j < 8; j++) Gtmp[(size_t)(gb + j) * CC + c] = acc[j];
}

__global__ void k_gate_bias(const float* __restrict__ Wih, const float* __restrict__ Icb,
                            const float* __restrict__ bih, const float* __restrict__ bhh,
                            float* __restrict__ gate_bias) {
    int g = blockIdx.x * 256 + threadIdx.x;
    float acc = bih[g] + bhh[g];
    for (int a = 0; a < AA; a++) acc += Wih[(size_t)g * VA + VV + a] * Icb[a];
    gate_bias[g] = acc;
}

__global__ void k_transpose(const float* __restrict__ src, float* __restrict__ dst,
                            int R, int Cc, int ld, int col0) {
    __shared__ float tile[32][33];
    int r0 = blockIdx.y * 32, c0 = blockIdx.x * 32;
    int tx = threadIdx.x, ty = threadIdx.y;  // 32 x 8
#pragma unroll
    for (int k = 0; k < 4; k++) {
        int r = r0 + ty + k * 8, c = c0 + tx;
        if (r < R && c < Cc) tile[ty + k * 8][tx] = src[(size_t)r * ld + col0 + c];
    }
    __syncthreads();
#pragma unroll
    for (int k = 0; k < 4; k++) {
        int c = c0 + ty + k * 8, r = r0 + tx;
        if (c < Cc && r < R) dst[(size_t)c * R + r] = tile[tx][ty + k * 8];
    }
}

__global__ void k_init(const int* __restrict__ labels, float* __restrict__ h,
                       float* __restrict__ cst, int* __restrict__ charr,
                       unsigned int* __restrict__ flags) {
    int b = blockIdx.x, t = threadIdx.x;  // 64 x 512
    h[b * HH + t] = 0.f;
    cst[b * HH + t] = 0.f;
    if (t == 0) charr[b] = labels[b * TT];
    int gidx = b * 512 + t;
    if (gidx < NFLAG) flags[gidx] = 0u;  // ws is 0xAA-poisoned -> must zero
}

// ---------------------------------------------------------------------------
// Zero-RMW grid barrier: per-block epoch flags (64B apart, parallel stores),
// wave-0 scans all 256 flags with relaxed agent loads (parallel reads).
// One release fence before the store, one acquire fence after the scan —
// same fence protocol rounds 3/4 proved correct cross-XCD on this chip.
// ---------------------------------------------------------------------------
__device__ __forceinline__ void gridbar(unsigned int* flags, unsigned int ep) {
    __syncthreads();
    int tid = threadIdx.x;
    if (tid == 0) {
        __threadfence();  // release this block's global writes
        __hip_atomic_store(flags + (blockIdx.x << 4), ep, __ATOMIC_RELEASE,
                           __HIP_MEMORY_SCOPE_AGENT);
    }
    if (tid < 64) {
        for (;;) {
            unsigned ok = 1u;
#pragma unroll
            for (int k = 0; k < 4; k++) {
                unsigned v = __hip_atomic_load(flags + ((tid + (k << 6)) << 4),
                                               __ATOMIC_RELAXED,
                                               __HIP_MEMORY_SCOPE_AGENT);
                ok &= (v >= ep) ? 1u : 0u;
            }
            if (__all((int)ok)) break;
            __builtin_amdgcn_s_sleep(2);
        }
        if (tid == 0) __threadfence();  // acquire other blocks' writes
    }
    __syncthreads();
}

// ---------------------------------------------------------------------------
// Persistent decode kernel: 256 blocks x 512 threads (1 block/CU)
// ---------------------------------------------------------------------------

struct KP {
    const float* X;      // [64,1024,512]
    const float* p0;     // [512]
    const float* v0;     // [512]
    const float* s0;     // [1]
    const float* P;      // [512 k][512 c]
    const float* GT;     // [512 c][2048 g]
    const float* WhhT;   // [512 c][2048 g]
    const float* Wih0T;  // [140 v][2048 g]
    const float* gateb;  // [2048]
    const float* Wout;   // [140,512]
    const float* bout;   // [140]
    float* h;            // [64,512]
    float* cst;          // [64,512]
    float* part_m;       // [64*4]
    float* part_l;       // [64*4]
    float* part_acc;     // [64*4,512]
    float* pg;           // [8,64,2048]
    float* qpart;        // [64*4,512]
    float* qbpart;       // [64*4]
    float* lpart;        // [64*4,LP]
    int* charr;          // [64]
    unsigned int* flags; // [NFLAG] barrier flags
    float* out;          // [64,128,140]
};

__global__ __launch_bounds__(512, 2) void k_decode(KP p) {
    const int bid = blockIdx.x, tid = threadIdx.x;
    const int w = tid >> 6, lane = tid & 63;
    const float inv_sqrt_a = 0.044194173824159216f;  // 1/sqrt(512)
    unsigned int ep = 0;

    __shared__ union {
        struct { float lacc[8][512]; float lm[8]; float ll[8]; float logl[VV]; } p1;
        struct { float coefL[16][4]; float actT[2048]; float wbuf[8192]; } p2;
        struct { float gl[512]; float hl[128]; } p3;
    } sm;

    for (int t = 0; t < TT; t++) {
        // ================= P1: combine (t-1) + flash ========================
        {
            int b = bid >> 2, chunk = bid & 3;

            // ---- logits combine + argmax + out-write for step t-1 ----
            if (t > 0 && chunk == 0) {
                if (tid < VV) {
                    float lv = p.bout[tid];
#pragma unroll
                    for (int q = 0; q < 4; q++) lv += p.lpart[(b * 4 + q) * LP + tid];
                    sm.p1.logl[tid] = lv;
                    p.out[((size_t)b * TT + (t - 1)) * VV + tid] = lv;
                }
                __syncthreads();
                if (w == 0) {
                    float bv = -INFINITY;
                    int bi = 0x7fffffff;
#pragma unroll
                    for (int k = 0; k < 3; k++) {
                        int v = lane + (k << 6);
                        if (v < VV) {
                            float x = sm.p1.logl[v];
                            if (x > bv) { bv = x; bi = v; }
                        }
                    }
#pragma unroll
                    for (int off = 1; off < 64; off <<= 1) {
                        float ov = __shfl_xor(bv, off, 64);
                        int oi = __shfl_xor(bi, off, 64);
                        if (ov > bv || (ov == bv && oi < bi)) { bv = ov; bi = oi; }
                    }
                    if (lane == 0) p.charr[b] = bi;
                }
            }

            // ---- build q (each lane holds features lane*8..+8) ----
            float qv[8];
            {
                const float4* pp = (const float4*)p.p0 + lane * 2;
                float4 A = pp[0], B = pp[1];
                qv[0] = A.x; qv[1] = A.y; qv[2] = A.z; qv[3] = A.w;
                qv[4] = B.x; qv[5] = B.y; qv[6] = B.z; qv[7] = B.w;
            }
            float qoff = p.s0[0];
            if (t > 0) {
#pragma unroll
                for (int q = 0; q < 4; q++) {
                    const float4* qp4 = (const float4*)(p.qpart + (b * 4 + q) * 512) + lane * 2;
                    float4 A = qp4[0], B = qp4[1];
                    qv[0] += A.x; qv[1] += A.y; qv[2] += A.z; qv[3] += A.w;
                    qv[4] += B.x; qv[5] += B.y; qv[6] += B.z; qv[7] += B.w;
                    qoff += p.qbpart[b * 4 + q];
                }
            }

            // ---- flash over 256 rows, 32 per wave, ILP-4 groups ----
            float m = -INFINITY, l = 0.f;
            float acc[8];
#pragma unroll
            for (int j = 0; j < 8; j++) acc[j] = 0.f;

            int base = chunk * 256 + w * 32;
#pragma unroll 2
            for (int g = 0; g < 8; g++) {
                const float4* xp = (const float4*)(p.X + ((size_t)b * SS + base + g * 4) * CC) + lane * 2;
                float4 a0 = xp[0],   b0 = xp[1];
                float4 a1 = xp[128], b1 = xp[129];
                float4 a2 = xp[256], b2 = xp[257];
                float4 a3 = xp[384], b3 = xp[385];
                float d0 = a0.x * qv[0] + a0.y * qv[1] + a0.z * qv[2] + a0.w * qv[3] +
                           b0.x * qv[4] + b0.y * qv[5] + b0.z * qv[6] + b0.w * qv[7];
                float d1 = a1.x * qv[0] + a1.y * qv[1] + a1.z * qv[2] + a1.w * qv[3] +
                           b1.x * qv[4] + b1.y * qv[5] + b1.z * qv[6] + b1.w * qv[7];
                float d2 = a2.x * qv[0] + a2.y * qv[1] + a2.z * qv[2] + a2.w * qv[3] +
                           b2.x * qv[4] + b2.y * qv[5] + b2.z * qv[6] + b2.w * qv[7];
                float d3 = a3.x * qv[0] + a3.y * qv[1] + a3.z * qv[2] + a3.w * qv[3] +
                           b3.x * qv[4] + b3.y * qv[5] + b3.z * qv[6] + b3.w * qv[7];
#pragma unroll
                for (int off = 1; off < 64; off <<= 1) {
                    d0 += __shfl_xor(d0, off, 64);
                    d1 += __shfl_xor(d1, off, 64);
                    d2 += __shfl_xor(d2, off, 64);
                    d3 += __shfl_xor(d3, off, 64);
                }
                float sc0 = (d0 + qoff) * inv_sqrt_a;
                float sc1 = (d1 + qoff) * inv_sqrt_a;
                float sc2 = (d2 + qoff) * inv_sqrt_a;
                float sc3 = (d3 + qoff) * inv_sqrt_a;
                float mn = fmaxf(fmaxf(fmaxf(sc0, sc1), fmaxf(sc2, sc3)), m);
                float f = expf(m - mn);  // m=-inf first group -> 0
                float e0 = expf(sc0 - mn), e1 = expf(sc1 - mn);
                float e2 = expf(sc2 - mn), e3 = expf(sc3 - mn);
                l = l * f + (e0 + e1) + (e2 + e3);
                acc[0] = acc[0] * f + e0 * a0.x + e1 * a1.x + e2 * a2.x + e3 * a3.x;
                acc[1] = acc[1] * f + e0 * a0.y + e1 * a1.y + e2 * a2.y + e3 * a3.y;
                acc[2] = acc[2] * f + e0 * a0.z + e1 * a1.z + e2 * a2.z + e3 * a3.z;
                acc[3] = acc[3] * f + e0 * a0.w + e1 * a1.w + e2 * a2.w + e3 * a3.w;
                acc[4] = acc[4] * f + e0 * b0.x + e1 * b1.x + e2 * b2.x + e3 * b3.x;
                acc[5] = acc[5] * f + e0 * b0.y + e1 * b1.y + e2 * b2.y + e3 * b3.y;
                acc[6] = acc[6] * f + e0 * b0.z + e1 * b1.z + e2 * b2.z + e3 * b3.z;
                acc[7] = acc[7] * f + e0 * b0.w + e1 * b1.w + e2 * b2.w + e3 * b3.w;
                m = mn;
            }

            // ---- combine 8 waves -> block partial ----
            __syncthreads();  // logl (t-1) fully consumed before lacc reuse
            if (lane == 0) sm.p1.lm[w] = m;
            __syncthreads();
            float M = sm.p1.lm[0];
#pragma unroll
            for (int j = 1; j < 8; j++) M = fmaxf(M, sm.p1.lm[j]);
            float f = expf(m - M);
            if (lane == 0) sm.p1.ll[w] = l * f;
#pragma unroll
            for (int j = 0; j < 8; j++) sm.p1.lacc[w][j * 64 + lane] = acc[j] * f;
            __syncthreads();
            {
                int ridx = (tid & 7) * 64 + (tid >> 3);  // element c=tid lives here
                float s = 0.f;
#pragma unroll
                for (int j = 0; j < 8; j++) s += sm.p1.lacc[j][ridx];
                p.part_acc[((b * 4 + chunk) << 9) + tid] = s;
            }
            if (tid == 0) {
                float lt = 0.f;
                for (int j = 0; j < 8; j++) lt += sm.p1.ll[j];
                p.part_m[b * 4 + chunk] = M;
                p.part_l[b * 4 + chunk] = lt;
            }
        }
        gridbar(p.flags, ++ep);

        // ================= P2: gates GEMM -> pg partials ====================
        {
            int cs = bid & 7, gt = (bid >> 3) & 7, bt = bid >> 6;
            int tg = tid & 63, tb = tid >> 6;  // tb = wave index (8), 2 b each

            if (cs < 4 && tid < 16) {
                int b = bt * 16 + tid;
                float m0 = p.part_m[b * 4 + 0], m1 = p.part_m[b * 4 + 1];
                float m2 = p.part_m[b * 4 + 2], m3 = p.part_m[b * 4 + 3];
                float M = fmaxf(fmaxf(m0, m1), fmaxf(m2, m3));
                float e0 = expf(m0 - M), e1 = expf(m1 - M);
                float e2 = expf(m2 - M), e3 = expf(m3 - M);
                float denom = e0 * p.part_l[b * 4 + 0] + e1 * p.part_l[b * 4 + 1] +
                              e2 * p.part_l[b * 4 + 2] + e3 * p.part_l[b * 4 + 3];
                float inv = 1.f / denom;
                sm.p2.coefL[tid][0] = e0 * inv; sm.p2.coefL[tid][1] = e1 * inv;
                sm.p2.coefL[tid][2] = e2 * inv; sm.p2.coefL[tid][3] = e3 * inv;
            }
            __syncthreads();
            // actT layout: [bb 16][cc 128] -> addr == idx (stride-1, conflict-free)
            if (cs < 4) {
#pragma unroll
                for (int k = 0; k < 4; k++) {
                    int idx = k * 512 + tid;
                    int bb = idx >> 7, cc = idx & 127;
                    const float* pa = p.part_acc + (size_t)((bt * 16 + bb) * 4) * 512 + cs * 128 + cc;
                    sm.p2.actT[idx] =
                        sm.p2.coefL[bb][0] * pa[0] + sm.p2.coefL[bb][1] * pa[512] +
                        sm.p2.coefL[bb][2] * pa[1024] + sm.p2.coefL[bb][3] * pa[1536];
                }
            } else {
#pragma unroll
                for (int k = 0; k < 4; k++) {
                    int idx = k * 512 + tid;
                    int bb = idx >> 7, cc = idx & 127;
                    sm.p2.actT[idx] = p.h[(bt * 16 + bb) * HH + (cs - 4) * 128 + cc];
                }
            }

            const float* W = (cs < 4) ? (p.GT + (size_t)(cs * 128) * G4)
                                      : (p.WhhT + (size_t)((cs - 4) * 128) * G4);
            float4 acc0 = make_float4(0, 0, 0, 0), acc1 = make_float4(0, 0, 0, 0);
            for (int cchunk = 0; cchunk < 4; cchunk++) {
                __syncthreads();
                {
                    const float4* Wr = (const float4*)(W + (size_t)(cchunk * 32) * G4 + gt * 256);
                    float4* wb4 = (float4*)sm.p2.wbuf;
#pragma unroll
                    for (int k = 0; k < 4; k++) {
                        int idx = k * 512 + tid;         // idx = i*64 + j4
                        int i = idx >> 6, j4 = idx & 63;
                        wb4[idx] = Wr[(size_t)i * (G4 / 4) + j4];
                    }
                }
                __syncthreads();
#pragma unroll 8
                for (int i = 0; i < 32; i++) {
                    float4 wv = *(const float4*)&sm.p2.wbuf[i * 256 + tg * 4];
                    float ax = sm.p2.actT[(tb * 2) * 128 + cchunk * 32 + i];
                    float ay = sm.p2.actT[(tb * 2 + 1) * 128 + cchunk * 32 + i];
                    acc0.x += ax * wv.x; acc0.y += ax * wv.y;
                    acc0.z += ax * wv.z; acc0.w += ax * wv.w;
                    acc1.x += ay * wv.x; acc1.y += ay * wv.y;
                    acc1.z += ay * wv.z; acc1.w += ay * wv.w;
                }
            }
            int b0 = bt * 16 + tb * 2;
            int g0 = gt * 256 + tg * 4;
            *(float4*)&p.pg[(size_t)(cs * BB + b0) * G4 + g0] = acc0;
            *(float4*)&p.pg[(size_t)(cs * BB + b0 + 1) * G4 + g0] = acc1;
        }
        gridbar(p.flags, ++ep);

        // ======== P3: gate sum + LSTM + logits/q'/qb partials ==============
        {
            int b = bid >> 2, q = bid & 3;
            int ch = p.charr[b];

            int gcls = tid >> 7, nloc = tid & 127;
            int gidx = gcls * 512 + q * 128 + nloc;
            float a = p.gateb[gidx] + p.Wih0T[(size_t)ch * G4 + gidx];
#pragma unroll
            for (int j = 0; j < 8; j++) a += p.pg[(size_t)(j * BB + b) * G4 + gidx];
            sm.p3.gl[tid] = a;
            __syncthreads();

            if (tid < 128) {
                float ig = 1.f / (1.f + expf(-sm.p3.gl[tid]));
                float fg = 1.f / (1.f + expf(-sm.p3.gl[128 + tid]));
                float gg = tanhf(sm.p3.gl[256 + tid]);
                float og = 1.f / (1.f + expf(-sm.p3.gl[384 + tid]));
                int n = q * 128 + tid;
                float cv = p.cst[b * HH + n];
                float cn = fg * cv + ig * gg;
                float hn = og * tanhf(cn);
                p.cst[b * HH + n] = cn;
                p.h[b * HH + n] = hn;
                sm.p3.hl[tid] = hn;
            }
            __syncthreads();

            // logits partials over this quarter's 128 h dims
            {
                int n2 = lane * 2;
                float h0 = sm.p3.hl[n2], h1 = sm.p3.hl[n2 + 1];
                for (int v = w; v < VV; v += 8) {
                    float2 w2 = *(const float2*)&p.Wout[(size_t)v * HH + q * 128 + n2];
                    float d = h0 * w2.x + h1 * w2.y;
#pragma unroll
                    for (int off = 1; off < 64; off <<= 1) d += __shfl_xor(d, off, 64);
                    if (lane == 0) p.lpart[(b * 4 + q) * LP + v] = d;
                }
            }

            // q' partial: qpart[b][q][c] = sum_{n in slice} h[n] * P[n][c]
            {
                float a2 = 0.f;
                const float* Pr = p.P + (size_t)(q * 128) * CC + tid;
#pragma unroll 4
                for (int j = 0; j < 128; j++) a2 += sm.p3.hl[j] * Pr[(size_t)j * CC];
                p.qpart[(b * 4 + q) * 512 + tid] = a2;
            }

            // qb partial
            if (w == 0) {
                int n2 = lane * 2;
                float pr = sm.p3.hl[n2] * p.v0[q * 128 + n2] +
                           sm.p3.hl[n2 + 1] * p.v0[q * 128 + n2 + 1];
#pragma unroll
                for (int off = 1; off < 64; off <<= 1) pr += __shfl_xor(pr, off, 64);
                if (lane == 0) p.qbpart[b * 4 + q] = pr;
            }
        }
        gridbar(p.flags, ++ep);
    }

    // final logits combine for t = 127
    {
        int b = bid >> 2, chunk = bid & 3;
        if (chunk == 0 && tid < VV) {
            float lv = p.bout[tid];
#pragma unroll
            for (int q = 0; q < 4; q++) lv += p.lpart[(b * 4 + q) * LP + tid];
            p.out[((size_t)b * TT + (TT - 1)) * VV + tid] = lv;
        }
    }
}

// ---------------------------------------------------------------------------

extern "C" void kernel_launch(void* const* d_in, const int* in_sizes, int n_in,
                              void* d_out, int out_size, void* d_ws, size_t ws_size,
                              hipStream_t stream) {
    const float* X    = (const float*)d_in[0];   // [64,1024,512]
    const int*   lab  = (const int*)d_in[1];     // [64,128]
    const float* Icw  = (const float*)d_in[2];   // [512,512]
    const float* Icb  = (const float*)d_in[3];   // [512]
    const float* Hcw  = (const float*)d_in[4];   // [512,512]
    const float* Hcb  = (const float*)d_in[5];   // [512]
    const float* Wih  = (const float*)d_in[6];   // [2048,652]
    const float* bih  = (const float*)d_in[7];   // [2048]
    const float* Whh  = (const float*)d_in[8];   // [2048,512]
    const float* bhh  = (const float*)d_in[9];   // [2048]
    const float* Wout = (const float*)d_in[10];  // [140,512]
    const float* bout = (const float*)d_in[11];  // [140]
    float* out = (float*)d_out;                  // [64,128,140]

    float* ws = (float*)d_ws;
    size_t off = 0;
    float* P        = ws + off; off += 512 * 512;
    float* GT       = ws + off; off += 512 * 2048;
    float* WhhT     = ws + off; off += 512 * 2048;
    float* Wih0T    = ws + off; off += 140 * 2048;
    float* gateb    = ws + off; off += 2048;
    float* p0       = ws + off; off += 512;
    float* v0       = ws + off; off += 512;
    float* s0       = ws + off; off += 64;
    float* h        = ws + off; off += 64 * 512;
    float* cst      = ws + off; off += 64 * 512;
    float* part_m   = ws + off; off += 256;
    float* part_l   = ws + off; off += 256;
    float* part_acc = ws + off; off += 64 * 4 * 512;
    float* pg       = ws + off; off += 8 * 64 * 2048;
    float* qpart    = ws + off; off += 64 * 4 * 512;
    float* qbpart   = ws + off; off += 256;
    float* lpart    = ws + off; off += 64 * 4 * LP;
    int*   charr    = (int*)(ws + off); off += 64;
    unsigned int* flags = (unsigned int*)(ws + off); off += NFLAG;
    if (ws_size < off * sizeof(float)) return;

    float* Gtmp = pg;  // pg only live after first P2; reuse for precompute

    k_small<<<1, 512, 0, stream>>>(Hcw, Hcb, Icw, Icb, p0, v0, s0);
    k_P<<<dim3(2, 512), 256, 0, stream>>>(Hcw, Icw, P);
    k_G<<<dim3(2, 256), 256, 0, stream>>>(Wih, Icw, Gtmp);
    k_transpose<<<dim3(16, 64), dim3(32, 8), 0, stream>>>(Gtmp, GT, 2048, 512, 512, 0);
    k_transpose<<<dim3(16, 64), dim3(32, 8), 0, stream>>>(Whh, WhhT, 2048, 512, 512, 0);
    k_transpose<<<dim3(5, 64), dim3(32, 8), 0, stream>>>(Wih, Wih0T, 2048, 140, 652, 0);
    k_gate_bias<<<8, 256, 0, stream>>>(Wih, Icb, bih, bhh, gateb);
    k_init<<<64, 512, 0, stream>>>(lab, h, cst, charr, flags);

    KP kp;
    kp.X = X; kp.p0 = p0; kp.v0 = v0; kp.s0 = s0; kp.P = P;
    kp.GT = GT; kp.WhhT = WhhT; kp.Wih0T = Wih0T; kp.gateb = gateb;
    kp.Wout = Wout; kp.bout = bout;
    kp.h = h; kp.cst = cst; kp.part_m = part_m; kp.part_l = part_l;
    kp.part_acc = part_acc; kp.pg = pg; kp.qpart = qpart; kp.qbpart = qbpart;
    kp.lpart = lpart; kp.charr = charr; kp.flags = flags; kp.out = out;

    void* args[] = { &kp };
    hipLaunchCooperativeKernel((const void*)k_decode, dim3(256), dim3(512),
                               args, 0, stream);
}